// Round 4
// baseline (829.194 us; speedup 1.0000x reference)
//
#include <hip/hip_runtime.h>
#include <hip/hip_cooperative_groups.h>
#include <math.h>

namespace cg = cooperative_groups;

#define BN    8
#define NN    1024
#define HH    64
#define ADIM  8
#define STEPS 5
#define K2    2048                 // N*E
#define ROWS  (BN*NN)              // 8192

typedef __attribute__((ext_vector_type(8))) short bf16x8;
typedef __attribute__((ext_vector_type(4))) float f32x4;

__device__ __forceinline__ unsigned short f2bf(float f) {
    unsigned int u = __float_as_uint(f);
    u += 0x7FFF + ((u >> 16) & 1);          // round-to-nearest-even
    return (unsigned short)(u >> 16);
}
__device__ __forceinline__ float bf2f(unsigned short h) {
    return __uint_as_float(((unsigned int)h) << 16);
}

// ---------------- single cooperative mega-kernel ----------------
// grid = 256 = 8 b x 32 row-tiles, 512 threads = 8 waves, 1 block/CU.
// Each block owns rows [n0, n0+32) of batch b; h lives in LDS for all steps.
// Phases separated by grid.sync(): P0 conv+prep+init | 5x step | head.
__global__ __launch_bounds__(512) void mega(
    const float* __restrict__ adj,
    const float* __restrict__ init_state,
    const float* __restrict__ ann,
    const float* __restrict__ We, const float* __restrict__ be,
    const float* __restrict__ Wg, const float* __restrict__ bg,
    const float* __restrict__ Wh, const float* __restrict__ bh,
    const float* __restrict__ Wo, const float* __restrict__ bo,
    unsigned short* __restrict__ adjb,
    unsigned short* __restrict__ edge_a,
    unsigned short* __restrict__ edge_b,
    unsigned short* __restrict__ wgp,
    unsigned short* __restrict__ wep,
    float* __restrict__ out)
{
    __shared__ __attribute__((aligned(16))) unsigned short Bs[2][64][264];  // 67.6 KB
    __shared__ __attribute__((aligned(16))) unsigned short Xhi[32][200];    // 12.8 KB
    __shared__ __attribute__((aligned(16))) unsigned short Xlo[32][200];    // 12.8 KB
    __shared__ __attribute__((aligned(16))) float          hf [32][68];     //  8.7 KB
    __shared__ __attribute__((aligned(16))) unsigned short HNhi[32][72];    //  4.6 KB
    __shared__ __attribute__((aligned(16))) unsigned short HNlo[32][72];    //  4.6 KB

    cg::grid_group grid = cg::this_grid();

    int t  = threadIdx.x;
    int b  = blockIdx.x >> 5;
    int mt = blockIdx.x & 31;
    int n0 = mt * 32;
    size_t hbase = ((size_t)(b * NN + n0)) * 64;

    // ======== P0a: adjacency fp32 -> bf16 (grid-strided, linear, coalesced) ========
    {
        int gtid = blockIdx.x * 512 + t;               // 0..131071
        const float4* src = (const float4*)adj;
        ushort4* dst = (ushort4*)adjb;
        #pragma unroll 8
        for (int i = 0; i < 64; ++i) {
            size_t idx = (size_t)gtid + (size_t)i * 131072;
            float4 v = src[idx];
            ushort4 o;
            o.x = f2bf(v.x); o.y = f2bf(v.y); o.z = f2bf(v.z); o.w = f2bf(v.w);
            dst[idx] = o;
        }
    }
    // ======== P0b: weight packs (blocks 0,1) ========
    if (blockIdx.x == 0) {
        for (int idx = t; idx < 12288; idx += 512) {
            int k = idx >> 6, c = idx & 63;
            float v = Wg[idx];
            unsigned short hi = f2bf(v), lo = f2bf(v - bf2f(hi));
            wgp[(size_t)c * 192 + k] = hi;
            wgp[(size_t)(64 + c) * 192 + k] = lo;
        }
    } else if (blockIdx.x == 1) {
        for (int idx = t; idx < 8192; idx += 512) {
            int k = idx >> 7, c = idx & 127;
            float v = We[idx];
            unsigned short hi = f2bf(v), lo = f2bf(v - bf2f(hi));
            wep[(size_t)c * 64 + k] = hi;
            wep[(size_t)(128 + c) * 64 + k] = lo;
        }
    }
    // ======== P0c: load h -> hf; edge-init for own 32 rows ========
    {
        int r = t >> 4, cg4 = (t & 15) * 4;
        float4 v = *(const float4*)(init_state + hbase + (size_t)r * 64 + cg4);
        hf[r][cg4 + 0] = v.x; hf[r][cg4 + 1] = v.y;
        hf[r][cg4 + 2] = v.z; hf[r][cg4 + 3] = v.w;
    }
    __syncthreads();
    {
        int r2 = t >> 4, tq = t & 15;
        int n = n0 + r2;
        float acc[8];
        #pragma unroll
        for (int m = 0; m < 8; ++m) acc[m] = be[tq * 8 + m];
        #pragma unroll 4
        for (int c = 0; c < 64; ++c) {
            float hv = hf[r2][c];
            float4 w0 = *(const float4*)&We[c * 128 + tq * 8];
            float4 w1 = *(const float4*)&We[c * 128 + tq * 8 + 4];
            acc[0] += hv * w0.x; acc[1] += hv * w0.y; acc[2] += hv * w0.z; acc[3] += hv * w0.w;
            acc[4] += hv * w1.x; acc[5] += hv * w1.y; acc[6] += hv * w1.z; acc[7] += hv * w1.w;
        }
        #pragma unroll
        for (int m = 0; m < 8; ++m) {
            int o = tq * 8 + m;
            int hp = o >> 1, e = o & 1;
            edge_a[((size_t)b * 64 + hp) * K2 + e * NN + n] = f2bf(acc[m]);
        }
    }
    __threadfence();
    grid.sync();

    // ======== step loop ========
    int lane = t & 63, w = t >> 6, l15 = lane & 15, q = lane >> 4;
    int dir = w >> 2, rh = (w >> 1) & 1, kc = w & 1;

    const unsigned short* Abase = adjb
        + ((size_t)(b * NN + n0 + rh * 16 + l15)) * 4096 + dir * K2 + kc * 128;

    int srow[4], scol[4];
    #pragma unroll
    for (int i = 0; i < 4; ++i) {
        int u = i * 512 + t;
        srow[i] = u >> 5; scol[i] = (u & 31) * 8;
    }

    const unsigned short* ein = edge_a;
    unsigned short* eout = edge_b;

    for (int s = 0; s < STEPS; ++s) {
        // ---- refresh X h-cols from hf ----
        {
            int r = t >> 4, cg4 = (t & 15) * 4;
            #pragma unroll
            for (int j = 0; j < 4; ++j) {
                float hv = hf[r][cg4 + j];
                unsigned short hi = f2bf(hv), lo = f2bf(hv - bf2f(hi));
                Xhi[r][128 + cg4 + j] = hi;
                Xlo[r][128 + cg4 + j] = lo;
            }
        }
        // ---- stage B chunk 0 ----
        const unsigned short* sptr[4];
        #pragma unroll
        for (int i = 0; i < 4; ++i)
            sptr[i] = ein + ((size_t)b * 64 + srow[i]) * K2 + scol[i];
        #pragma unroll
        for (int i = 0; i < 4; ++i)
            *(uint4*)&Bs[0][srow[i]][scol[i]] = *(const uint4*)(sptr[i]);
        __syncthreads();

        f32x4 acc[4];
        #pragma unroll
        for (int ct = 0; ct < 4; ++ct) acc[ct] = (f32x4){0.f, 0.f, 0.f, 0.f};

        bf16x8 af[4];
        #pragma unroll
        for (int ks = 0; ks < 4; ++ks)
            af[ks] = *(const bf16x8*)(Abase + ks * 32 + q * 8);

        #pragma unroll
        for (int c = 0; c < 8; ++c) {
            int buf = c & 1;
            uint4 g[4];
            bf16x8 afn[4];
            if (c < 7) {
                #pragma unroll
                for (int i = 0; i < 4; ++i)
                    g[i] = *(const uint4*)(sptr[i] + (c + 1) * 256);
                #pragma unroll
                for (int ks = 0; ks < 4; ++ks)
                    afn[ks] = *(const bf16x8*)(Abase + (c + 1) * 256 + ks * 32 + q * 8);
            }
            #pragma unroll
            for (int ks = 0; ks < 4; ++ks) {
                #pragma unroll
                for (int ct = 0; ct < 4; ++ct) {
                    bf16x8 bfr = *(const bf16x8*)&Bs[buf][ct * 16 + l15][kc * 128 + ks * 32 + q * 8];
                    acc[ct] = __builtin_amdgcn_mfma_f32_16x16x32_bf16(af[ks], bfr, acc[ct], 0, 0, 0);
                }
            }
            if (c < 7) {
                #pragma unroll
                for (int i = 0; i < 4; ++i)
                    *(uint4*)&Bs[buf ^ 1][srow[i]][scol[i]] = g[i];
                #pragma unroll
                for (int ks = 0; ks < 4; ++ks) af[ks] = afn[ks];
            }
            __syncthreads();
        }

        // ---- reduce kc-pairs via LDS (overlaid on dead Bs region) ----
        float (*red)[16][68] = (float (*)[16][68])(&Bs[0][0][0]);
        int gg = w >> 1;                                 // dir*2 + rh
        if (kc == 1) {
            #pragma unroll
            for (int ct = 0; ct < 4; ++ct)
                #pragma unroll
                for (int i = 0; i < 4; ++i)
                    red[gg][q * 4 + i][ct * 16 + l15] = acc[ct][i];
        }
        __syncthreads();
        if (kc == 0) {
            #pragma unroll
            for (int ct = 0; ct < 4; ++ct)
                #pragma unroll
                for (int i = 0; i < 4; ++i) {
                    float v = acc[ct][i] + red[gg][q * 4 + i][ct * 16 + l15];
                    unsigned short hi = f2bf(v), lo = f2bf(v - bf2f(hi));
                    int r  = rh * 16 + q * 4 + i;
                    int cc2 = dir * 64 + ct * 16 + l15;
                    Xhi[r][cc2] = hi;
                    Xlo[r][cc2] = lo;
                }
        }
        __syncthreads();

        // ---- gate (MFMA, hi/lo split): wave -> (mg, 16-col tile) ----
        int mg = w & 1, cg16 = w >> 1;
        int arow = mg * 16 + l15;
        int cc = cg16 * 16 + l15;
        const unsigned short* wcol = wgp + (size_t)cc * 192;
        f32x4 as = (f32x4){0.f, 0.f, 0.f, 0.f}, az;

        #pragma unroll
        for (int ks = 0; ks < 4; ++ks) {                 // shared K = 0..127
            bf16x8 ah = *(const bf16x8*)&Xhi[arow][ks * 32 + q * 8];
            bf16x8 al = *(const bf16x8*)&Xlo[arow][ks * 32 + q * 8];
            const unsigned short* wb = wcol + ks * 32 + q * 8;
            bf16x8 bh = *(const bf16x8*)wb;
            bf16x8 bl = *(const bf16x8*)(wb + 64 * 192);
            as = __builtin_amdgcn_mfma_f32_16x16x32_bf16(ah, bh, as, 0, 0, 0);
            as = __builtin_amdgcn_mfma_f32_16x16x32_bf16(ah, bl, as, 0, 0, 0);
            as = __builtin_amdgcn_mfma_f32_16x16x32_bf16(al, bh, as, 0, 0, 0);
        }
        az = as;
        #pragma unroll
        for (int ks = 4; ks < 6; ++ks) {                 // z extra: K=128..191 (h)
            bf16x8 ah = *(const bf16x8*)&Xhi[arow][ks * 32 + q * 8];
            bf16x8 al = *(const bf16x8*)&Xlo[arow][ks * 32 + q * 8];
            const unsigned short* wb = wcol + ks * 32 + q * 8;
            bf16x8 bh = *(const bf16x8*)wb;
            bf16x8 bl = *(const bf16x8*)(wb + 64 * 192);
            az = __builtin_amdgcn_mfma_f32_16x16x32_bf16(ah, bh, az, 0, 0, 0);
            az = __builtin_amdgcn_mfma_f32_16x16x32_bf16(ah, bl, az, 0, 0, 0);
            az = __builtin_amdgcn_mfma_f32_16x16x32_bf16(al, bh, az, 0, 0, 0);
        }
        __syncthreads();   // all waves done reading h slots before zh overwrite

        float zv[4], hv[4];
        float bgv = bg[cc];
        #pragma unroll
        for (int i = 0; i < 4; ++i) {
            int r = mg * 16 + q * 4 + i;
            float z = 1.f / (1.f + __expf(-(az[i] + bgv)));
            float h = hf[r][cc];
            zv[i] = z; hv[i] = h;
            float zh = z * h;
            unsigned short hi = f2bf(zh), lo = f2bf(zh - bf2f(hi));
            Xhi[r][128 + cc] = hi;
            Xlo[r][128 + cc] = lo;
        }
        __syncthreads();

        #pragma unroll
        for (int ks = 4; ks < 6; ++ks) {                 // ht extra: K=128..191 (zh)
            bf16x8 ah = *(const bf16x8*)&Xhi[arow][ks * 32 + q * 8];
            bf16x8 al = *(const bf16x8*)&Xlo[arow][ks * 32 + q * 8];
            const unsigned short* wb = wcol + ks * 32 + q * 8;
            bf16x8 bh = *(const bf16x8*)wb;
            bf16x8 bl = *(const bf16x8*)(wb + 64 * 192);
            as = __builtin_amdgcn_mfma_f32_16x16x32_bf16(ah, bh, as, 0, 0, 0);
            as = __builtin_amdgcn_mfma_f32_16x16x32_bf16(ah, bl, as, 0, 0, 0);
            as = __builtin_amdgcn_mfma_f32_16x16x32_bf16(al, bh, as, 0, 0, 0);
        }

        #pragma unroll
        for (int i = 0; i < 4; ++i) {
            int r = mg * 16 + q * 4 + i;
            float ht = tanhf(as[i] + bgv);
            float z  = zv[i];
            float hn = (1.f - z) * hv[i] + z * ht;
            hf[r][cc] = hn;
            if (s < STEPS - 1) {
                unsigned short hi = f2bf(hn), lo = f2bf(hn - bf2f(hi));
                HNhi[r][cc] = hi;
                HNlo[r][cc] = lo;
            }
        }

        if (s < STEPS - 1) {
            __syncthreads();
            // ---- edge projection (MFMA, hi/lo split), transposed bf16 store ----
            int me = w & 1, cb2 = (w >> 1) * 2;
            int erow = me * 16 + l15;
            f32x4 ae[2];
            ae[0] = ae[1] = (f32x4){0.f, 0.f, 0.f, 0.f};
            #pragma unroll
            for (int ks = 0; ks < 2; ++ks) {
                bf16x8 ah = *(const bf16x8*)&HNhi[erow][ks * 32 + q * 8];
                bf16x8 al = *(const bf16x8*)&HNlo[erow][ks * 32 + q * 8];
                #pragma unroll
                for (int p = 0; p < 2; ++p) {
                    int ec = (cb2 + p) * 16 + l15;
                    const unsigned short* wb = wep + (size_t)ec * 64 + ks * 32 + q * 8;
                    bf16x8 bh = *(const bf16x8*)wb;
                    bf16x8 bl = *(const bf16x8*)(wb + 128 * 64);
                    ae[p] = __builtin_amdgcn_mfma_f32_16x16x32_bf16(ah, bh, ae[p], 0, 0, 0);
                    ae[p] = __builtin_amdgcn_mfma_f32_16x16x32_bf16(ah, bl, ae[p], 0, 0, 0);
                    ae[p] = __builtin_amdgcn_mfma_f32_16x16x32_bf16(al, bh, ae[p], 0, 0, 0);
                }
            }
            #pragma unroll
            for (int p = 0; p < 2; ++p) {
                int ec = (cb2 + p) * 16 + l15;
                float bev = be[ec];
                int hp2 = ec >> 1, e = ec & 1;
                size_t ebase = ((size_t)b * 64 + hp2) * K2 + (size_t)e * NN
                             + n0 + me * 16 + q * 4;
                ushort4 ev;
                ev.x = f2bf(ae[p][0] + bev);
                ev.y = f2bf(ae[p][1] + bev);
                ev.z = f2bf(ae[p][2] + bev);
                ev.w = f2bf(ae[p][3] + bev);
                *(ushort4*)(eout + ebase) = ev;
            }
            __threadfence();
            grid.sync();
            const unsigned short* tmp = ein; ein = eout; eout = (unsigned short*)tmp;
        }
    }

    // ======== head: 32 rows per block, h from hf ========
    __syncthreads();
    {
        int r = t >> 4, hq = (t & 15) * 4;               // 16 lanes per row, 4 cols each
        int row = b * NN + n0 + r;
        float av[ADIM];
        #pragma unroll
        for (int j = 0; j < ADIM; ++j) av[j] = ann[(size_t)row * ADIM + j];
        float acc[4];
        #pragma unroll
        for (int i = 0; i < 4; ++i) acc[i] = bh[hq + i];
        #pragma unroll 8
        for (int k = 0; k < 64; ++k) {
            float hv = hf[r][k];
            float4 wv = *(const float4*)&Wh[k * 64 + hq];
            acc[0] += hv * wv.x; acc[1] += hv * wv.y;
            acc[2] += hv * wv.z; acc[3] += hv * wv.w;
        }
        #pragma unroll
        for (int k = 0; k < ADIM; ++k) {
            float4 wv = *(const float4*)&Wh[(64 + k) * 64 + hq];
            acc[0] += av[k] * wv.x; acc[1] += av[k] * wv.y;
            acc[2] += av[k] * wv.z; acc[3] += av[k] * wv.w;
        }
        float v = 0.f;
        #pragma unroll
        for (int i = 0; i < 4; ++i)
            v += tanhf(acc[i]) * Wo[hq + i];
        #pragma unroll
        for (int m = 8; m; m >>= 1) v += __shfl_xor(v, m, 64);
        if ((t & 15) == 0) out[row] = v + bo[0];
    }
}

extern "C" void kernel_launch(void* const* d_in, const int* in_sizes, int n_in,
                              void* d_out, int out_size, void* d_ws, size_t ws_size,
                              hipStream_t stream) {
    const float* init_state = (const float*)d_in[0];
    const float* ann = (const float*)d_in[1];
    const float* adj = (const float*)d_in[2];
    const float* We  = (const float*)d_in[3];
    const float* be  = (const float*)d_in[4];
    const float* Wg  = (const float*)d_in[5];
    const float* bg  = (const float*)d_in[6];
    const float* Wh  = (const float*)d_in[7];
    const float* bh  = (const float*)d_in[8];
    const float* Wo  = (const float*)d_in[9];
    const float* bo  = (const float*)d_in[10];
    float* out = (float*)d_out;

    // ws: adjb 64MB | edge_a 2MB | edge_b 2MB | wgp 48KB | wep 32KB
    char* wsb = (char*)d_ws;
    unsigned short* adjb   = (unsigned short*)wsb;
    unsigned short* edge_a = (unsigned short*)(wsb + 67108864);
    unsigned short* edge_b = (unsigned short*)(wsb + 69206016);
    unsigned short* wgp    = (unsigned short*)(wsb + 71303168);
    unsigned short* wep    = (unsigned short*)(wsb + 71352320);

    void* args[] = {
        (void*)&adj, (void*)&init_state, (void*)&ann,
        (void*)&We, (void*)&be, (void*)&Wg, (void*)&bg,
        (void*)&Wh, (void*)&bh, (void*)&Wo, (void*)&bo,
        (void*)&adjb, (void*)&edge_a, (void*)&edge_b,
        (void*)&wgp, (void*)&wep, (void*)&out
    };
    hipLaunchCooperativeKernel((const void*)mega, dim3(256), dim3(512),
                               args, 0, stream);
}

// Round 5
// 381.579 us; speedup vs baseline: 2.1731x; 2.1731x over previous
//
#include <hip/hip_runtime.h>
#include <math.h>

#define BN    8
#define NN    1024
#define HH    64
#define ADIM  8
#define STEPS 5
#define K2    2048                 // N*E
#define ROWS  (BN*NN)              // 8192

typedef __attribute__((ext_vector_type(8))) short bf16x8;
typedef __attribute__((ext_vector_type(4))) float f32x4;

__device__ __forceinline__ unsigned short f2bf(float f) {
    unsigned int u = __float_as_uint(f);
    u += 0x7FFF + ((u >> 16) & 1);          // round-to-nearest-even
    return (unsigned short)(u >> 16);
}
__device__ __forceinline__ float bf2f(unsigned short h) {
    return __uint_as_float(((unsigned int)h) << 16);
}

// lgkm-only barrier: LDS ops drained, global loads stay in flight (no vmcnt drain)
__device__ __forceinline__ void lgkm_barrier() {
    asm volatile("s_waitcnt lgkmcnt(0)" ::: "memory");
    __builtin_amdgcn_s_barrier();
    asm volatile("" ::: "memory");
}

// ---------------- one-time: adjacency fp32 -> bf16 ----------------
__global__ __launch_bounds__(256) void conv_adj(
    const float* __restrict__ in, unsigned short* __restrict__ out)
{
    int tid = blockIdx.x * 256 + threadIdx.x;     // 0..2097151
    #pragma unroll
    for (int i = 0; i < 4; ++i) {
        size_t idx = (size_t)tid + (size_t)i * 2097152;
        float4 v = ((const float4*)in)[idx];
        ushort4 o;
        o.x = f2bf(v.x); o.y = f2bf(v.y); o.z = f2bf(v.z); o.w = f2bf(v.w);
        ((ushort4*)out)[idx] = o;
    }
}

// ---------------- one-time: Wg/We -> transposed bf16 hi/lo packs ----------
__global__ __launch_bounds__(256) void prep_pack(
    const float* __restrict__ Wg, const float* __restrict__ We,
    unsigned short* __restrict__ wgp, unsigned short* __restrict__ wep)
{
    int t = blockIdx.x * 256 + threadIdx.x;
    if (t < 12288) {
        int k = t >> 6, c = t & 63;
        float v = Wg[t];
        unsigned short hi = f2bf(v);
        unsigned short lo = f2bf(v - bf2f(hi));
        wgp[(size_t)c * 192 + k] = hi;
        wgp[(size_t)(64 + c) * 192 + k] = lo;
    } else if (t < 20480) {
        int u = t - 12288;
        int k = u >> 7, c = u & 127;
        float v = We[u];
        unsigned short hi = f2bf(v);
        unsigned short lo = f2bf(v - bf2f(hi));
        wep[(size_t)c * 64 + k] = hi;
        wep[(size_t)(128 + c) * 64 + k] = lo;
    }
}

// ---------------- init: h_ws = initial_state; edge_t = f(initial_state) ----------
__global__ __launch_bounds__(256) void init_kernel(
    const float* __restrict__ init_state,
    const float* __restrict__ We, const float* __restrict__ be,
    float* __restrict__ h_ws, unsigned short* __restrict__ edge_t)
{
    __shared__ float h_lds[4][65];
    int t = threadIdx.x;
    int r = t >> 6, hp = t & 63;
    int row = blockIdx.x * 4 + r;
    float hv = init_state[(size_t)row * 64 + hp];
    h_ws[(size_t)row * 64 + hp] = hv;
    h_lds[r][hp] = hv;
    __syncthreads();
    int b = row >> 10, n = row & 1023;
    #pragma unroll
    for (int e = 0; e < 2; ++e) {
        float acc = be[hp * 2 + e];
        #pragma unroll 8
        for (int c = 0; c < 64; ++c)
            acc += h_lds[r][c] * We[c * 128 + hp * 2 + e];
        edge_t[((size_t)b * 64 + hp) * K2 + e * NN + n] = f2bf(acc);
    }
}

// ---------------- fused step: pipelined GEMM + gate + edge, 32 rows/block ----------
// grid = 256 = 8 b x 32 row-tiles; 512 threads = 8 waves.
// K-loop: depth-2 prefetch (gA/gB, afA/afB), lgkm-only barriers -> counted vmcnt,
// global loads never drained to 0 inside the loop (T3/T4).
__global__ __launch_bounds__(512) void step_kernel(
    const unsigned short* __restrict__ adjb,     // [b][n][4096] bf16
    const unsigned short* __restrict__ ein,      // [b][64][2048] bf16
    unsigned short* __restrict__ eout,           // [b][64][2048] bf16
    float* __restrict__ h_ws,
    const unsigned short* __restrict__ wgp,      // [2][64][192]
    const unsigned short* __restrict__ wep,      // [2][128][64]
    const float* __restrict__ bg,
    const float* __restrict__ be,
    int do_edge)
{
    __shared__ __attribute__((aligned(16))) unsigned short Bs[2][64][264];  // 67.6 KB
    __shared__ __attribute__((aligned(16))) unsigned short Xhi[32][200];    // 12.8 KB
    __shared__ __attribute__((aligned(16))) unsigned short Xlo[32][200];    // 12.8 KB
    __shared__ __attribute__((aligned(16))) float          hf [32][68];     //  8.7 KB
    __shared__ __attribute__((aligned(16))) unsigned short HNhi[32][72];    //  4.6 KB
    __shared__ __attribute__((aligned(16))) unsigned short HNlo[32][72];    //  4.6 KB

    int t  = threadIdx.x;
    int b  = blockIdx.x >> 5;
    int mt = blockIdx.x & 31;
    int n0 = mt * 32;
    size_t hbase = ((size_t)(b * NN + n0)) * 64;

    int lane = t & 63, w = t >> 6, l15 = lane & 15, q = lane >> 4;
    int dir = w >> 2, rh = (w >> 1) & 1, kc = w & 1;

    const unsigned short* Abase = adjb
        + ((size_t)(b * NN + n0 + rh * 16 + l15)) * 4096 + dir * K2 + kc * 128;

    // staging map (conflict-free: consecutive lanes -> consecutive 16B)
    int srow[4], scol[4];
    const unsigned short* sptr[4];
    #pragma unroll
    for (int i = 0; i < 4; ++i) {
        int u = i * 512 + t;
        srow[i] = u >> 5; scol[i] = (u & 31) * 8;
        sptr[i] = ein + ((size_t)b * 64 + srow[i]) * K2 + scol[i];
    }

    // ---- h load (issue early) ----
    int hr = t >> 4, hcg = (t & 15) * 4;
    float4 hv4 = *(const float4*)(h_ws + hbase + (size_t)hr * 64 + hcg);

    // ---- prologue: issue stage(0), stage(1), A(0), A(1) ----
    uint4 gA[4], gB[4];
    #pragma unroll
    for (int i = 0; i < 4; ++i) gA[i] = *(const uint4*)(sptr[i]);
    #pragma unroll
    for (int i = 0; i < 4; ++i) gB[i] = *(const uint4*)(sptr[i] + 256);
    bf16x8 afA[4], afB[4];
    #pragma unroll
    for (int ks = 0; ks < 4; ++ks)
        afA[ks] = *(const bf16x8*)(Abase + ks * 32 + q * 8);
    #pragma unroll
    for (int ks = 0; ks < 4; ++ks)
        afB[ks] = *(const bf16x8*)(Abase + 256 + ks * 32 + q * 8);

    // ---- h -> X[.][128..191] (hi/lo) + hf (overlaps with in-flight loads) ----
    {
        float vv[4] = {hv4.x, hv4.y, hv4.z, hv4.w};
        #pragma unroll
        for (int j = 0; j < 4; ++j) {
            float hv = vv[j];
            unsigned short hi = f2bf(hv), lo = f2bf(hv - bf2f(hi));
            Xhi[hr][128 + hcg + j] = hi;
            Xlo[hr][128 + hcg + j] = lo;
            hf[hr][hcg + j] = hv;
        }
    }

    // ---- write stage(0) to LDS (compiler emits counted vmcnt for gA) ----
    #pragma unroll
    for (int i = 0; i < 4; ++i)
        *(uint4*)&Bs[0][srow[i]][scol[i]] = gA[i];
    lgkm_barrier();

    f32x4 acc[4];
    #pragma unroll
    for (int ct = 0; ct < 4; ++ct) acc[ct] = (f32x4){0.f, 0.f, 0.f, 0.f};

    #pragma unroll
    for (int c = 0; c < 8; ++c) {
        const int par = c & 1;
        // issue stage(c+2) into set parity (c&1) (that set was LDS-written last chunk)
        if (c < 6) {
            #pragma unroll
            for (int i = 0; i < 4; ++i) {
                uint4 v = *(const uint4*)(sptr[i] + (c + 2) * 256);
                if (par == 0) gA[i] = v; else gB[i] = v;
            }
        }
        // MFMA on chunk c: af set parity, Bs[parity]
        #pragma unroll
        for (int ks = 0; ks < 4; ++ks) {
            bf16x8 a = (par == 0) ? afA[ks] : afB[ks];
            #pragma unroll
            for (int ct = 0; ct < 4; ++ct) {
                bf16x8 bfr = *(const bf16x8*)&Bs[par][ct * 16 + l15][kc * 128 + ks * 32 + q * 8];
                acc[ct] = __builtin_amdgcn_mfma_f32_16x16x32_bf16(a, bfr, acc[ct], 0, 0, 0);
            }
        }
        // reload A(c+2) into the just-consumed af set
        if (c < 6) {
            #pragma unroll
            for (int ks = 0; ks < 4; ++ks) {
                bf16x8 v = *(const bf16x8*)(Abase + (c + 2) * 256 + ks * 32 + q * 8);
                if (par == 0) afA[ks] = v; else afB[ks] = v;
            }
        }
        // ds_write stage(c+1) (parity !par) into Bs[!par]; counted vmcnt auto-emitted
        if (c < 7) {
            #pragma unroll
            for (int i = 0; i < 4; ++i) {
                uint4 v = (par == 0) ? gB[i] : gA[i];
                *(uint4*)&Bs[par ^ 1][srow[i]][scol[i]] = v;
            }
        }
        lgkm_barrier();
    }

    // ---- reduce kc-pairs via LDS (overlaid on dead Bs region) ----
    float (*red)[16][68] = (float (*)[16][68])(&Bs[0][0][0]);   // 17.4 KB
    int gg = w >> 1;                                            // dir*2 + rh
    if (kc == 1) {
        #pragma unroll
        for (int ct = 0; ct < 4; ++ct)
            #pragma unroll
            for (int i = 0; i < 4; ++i)
                red[gg][q * 4 + i][ct * 16 + l15] = acc[ct][i];
    }
    __syncthreads();
    if (kc == 0) {
        #pragma unroll
        for (int ct = 0; ct < 4; ++ct)
            #pragma unroll
            for (int i = 0; i < 4; ++i) {
                float v = acc[ct][i] + red[gg][q * 4 + i][ct * 16 + l15];
                unsigned short hi = f2bf(v), lo = f2bf(v - bf2f(hi));
                int r  = rh * 16 + q * 4 + i;
                int cc2 = dir * 64 + ct * 16 + l15;
                Xhi[r][cc2] = hi;
                Xlo[r][cc2] = lo;
            }
    }
    __syncthreads();

    // ---- gate (MFMA, hi/lo split): wave -> (mg, 16-col tile) ----
    int mg = w & 1, cg16 = w >> 1;
    int arow = mg * 16 + l15;
    int cc = cg16 * 16 + l15;
    const unsigned short* wcol = wgp + (size_t)cc * 192;
    f32x4 as = (f32x4){0.f, 0.f, 0.f, 0.f}, az;

    #pragma unroll
    for (int ks = 0; ks < 4; ++ks) {                 // shared K = 0..127 (a_in|a_out)
        bf16x8 ah = *(const bf16x8*)&Xhi[arow][ks * 32 + q * 8];
        bf16x8 al = *(const bf16x8*)&Xlo[arow][ks * 32 + q * 8];
        const unsigned short* wb = wcol + ks * 32 + q * 8;
        bf16x8 bh = *(const bf16x8*)wb;
        bf16x8 bl = *(const bf16x8*)(wb + 64 * 192);
        as = __builtin_amdgcn_mfma_f32_16x16x32_bf16(ah, bh, as, 0, 0, 0);
        as = __builtin_amdgcn_mfma_f32_16x16x32_bf16(ah, bl, as, 0, 0, 0);
        as = __builtin_amdgcn_mfma_f32_16x16x32_bf16(al, bh, as, 0, 0, 0);
    }
    az = as;
    #pragma unroll
    for (int ks = 4; ks < 6; ++ks) {                 // z extra: K = 128..191 (h)
        bf16x8 ah = *(const bf16x8*)&Xhi[arow][ks * 32 + q * 8];
        bf16x8 al = *(const bf16x8*)&Xlo[arow][ks * 32 + q * 8];
        const unsigned short* wb = wcol + ks * 32 + q * 8;
        bf16x8 bh = *(const bf16x8*)wb;
        bf16x8 bl = *(const bf16x8*)(wb + 64 * 192);
        az = __builtin_amdgcn_mfma_f32_16x16x32_bf16(ah, bh, az, 0, 0, 0);
        az = __builtin_amdgcn_mfma_f32_16x16x32_bf16(ah, bl, az, 0, 0, 0);
        az = __builtin_amdgcn_mfma_f32_16x16x32_bf16(al, bh, az, 0, 0, 0);
    }
    __syncthreads();   // all waves done reading h slots before zh overwrite

    float zv[4], hv[4];
    float bgv = bg[cc];
    #pragma unroll
    for (int i = 0; i < 4; ++i) {
        int r = mg * 16 + q * 4 + i;
        float z = 1.f / (1.f + __expf(-(az[i] + bgv)));
        float h = hf[r][cc];
        zv[i] = z; hv[i] = h;
        float zh = z * h;
        unsigned short hi = f2bf(zh), lo = f2bf(zh - bf2f(hi));
        Xhi[r][128 + cc] = hi;
        Xlo[r][128 + cc] = lo;
    }
    __syncthreads();

    #pragma unroll
    for (int ks = 4; ks < 6; ++ks) {                 // ht extra: K = 128..191 (zh)
        bf16x8 ah = *(const bf16x8*)&Xhi[arow][ks * 32 + q * 8];
        bf16x8 al = *(const bf16x8*)&Xlo[arow][ks * 32 + q * 8];
        const unsigned short* wb = wcol + ks * 32 + q * 8;
        bf16x8 bh = *(const bf16x8*)wb;
        bf16x8 bl = *(const bf16x8*)(wb + 64 * 192);
        as = __builtin_amdgcn_mfma_f32_16x16x32_bf16(ah, bh, as, 0, 0, 0);
        as = __builtin_amdgcn_mfma_f32_16x16x32_bf16(ah, bl, as, 0, 0, 0);
        as = __builtin_amdgcn_mfma_f32_16x16x32_bf16(al, bh, as, 0, 0, 0);
    }

    #pragma unroll
    for (int i = 0; i < 4; ++i) {
        int r = mg * 16 + q * 4 + i;
        float ht = tanhf(as[i] + bgv);
        float z  = zv[i];
        float hn = (1.f - z) * hv[i] + z * ht;
        h_ws[hbase + (size_t)r * 64 + cc] = hn;
        if (do_edge) {
            unsigned short hi = f2bf(hn), lo = f2bf(hn - bf2f(hi));
            HNhi[r][cc] = hi;
            HNlo[r][cc] = lo;
        }
    }
    if (!do_edge) return;
    __syncthreads();

    // ---- edge projection (MFMA, hi/lo split), transposed bf16 store ----
    int me = w & 1, cb2 = (w >> 1) * 2;
    int erow = me * 16 + l15;
    f32x4 ae[2];
    ae[0] = ae[1] = (f32x4){0.f, 0.f, 0.f, 0.f};
    #pragma unroll
    for (int ks = 0; ks < 2; ++ks) {
        bf16x8 ah = *(const bf16x8*)&HNhi[erow][ks * 32 + q * 8];
        bf16x8 al = *(const bf16x8*)&HNlo[erow][ks * 32 + q * 8];
        #pragma unroll
        for (int p = 0; p < 2; ++p) {
            int ec = (cb2 + p) * 16 + l15;
            const unsigned short* wb = wep + (size_t)ec * 64 + ks * 32 + q * 8;
            bf16x8 bh = *(const bf16x8*)wb;
            bf16x8 bl = *(const bf16x8*)(wb + 128 * 64);
            ae[p] = __builtin_amdgcn_mfma_f32_16x16x32_bf16(ah, bh, ae[p], 0, 0, 0);
            ae[p] = __builtin_amdgcn_mfma_f32_16x16x32_bf16(ah, bl, ae[p], 0, 0, 0);
            ae[p] = __builtin_amdgcn_mfma_f32_16x16x32_bf16(al, bh, ae[p], 0, 0, 0);
        }
    }
    #pragma unroll
    for (int p = 0; p < 2; ++p) {
        int ec = (cb2 + p) * 16 + l15;
        float bev = be[ec];
        int hp2 = ec >> 1, e = ec & 1;
        size_t ebase = ((size_t)b * 64 + hp2) * K2 + (size_t)e * NN
                     + n0 + me * 16 + q * 4;
        ushort4 ev;
        ev.x = f2bf(ae[p][0] + bev);
        ev.y = f2bf(ae[p][1] + bev);
        ev.z = f2bf(ae[p][2] + bev);
        ev.w = f2bf(ae[p][3] + bev);
        *(ushort4*)(eout + ebase) = ev;
    }
}

// ---------------- output head ----------
__global__ __launch_bounds__(256) void head_kernel(
    const float* __restrict__ h_ws, const float* __restrict__ ann,
    const float* __restrict__ Wh, const float* __restrict__ bh,
    const float* __restrict__ Wo, const float* __restrict__ bo,
    float* __restrict__ out)
{
    __shared__ float Wh_l[72 * 64];
    __shared__ float ha[4][72];
    int t = threadIdx.x;
    #pragma unroll
    for (int l = 0; l < 18; ++l) {
        int idx = t + l * 256;
        Wh_l[idx] = Wh[idx];
    }
    int r = t >> 6, hp = t & 63;
    int row = blockIdx.x * 4 + r;
    ha[r][hp] = h_ws[(size_t)row * 64 + hp];
    if (hp < ADIM) ha[r][64 + hp] = ann[(size_t)row * ADIM + hp];
    __syncthreads();

    float acc = bh[hp];
    #pragma unroll 8
    for (int k = 0; k < 72; ++k)
        acc += ha[r][k] * Wh_l[k * 64 + hp];
    float v = tanhf(acc) * Wo[hp];
    #pragma unroll
    for (int o = 32; o; o >>= 1) v += __shfl_down(v, o, 64);
    if (hp == 0) out[row] = v + bo[0];
}

extern "C" void kernel_launch(void* const* d_in, const int* in_sizes, int n_in,
                              void* d_out, int out_size, void* d_ws, size_t ws_size,
                              hipStream_t stream) {
    const float* init_state = (const float*)d_in[0];
    const float* ann = (const float*)d_in[1];
    const float* adj = (const float*)d_in[2];
    const float* We  = (const float*)d_in[3];
    const float* be  = (const float*)d_in[4];
    const float* Wg  = (const float*)d_in[5];
    const float* bg  = (const float*)d_in[6];
    const float* Wh  = (const float*)d_in[7];
    const float* bh  = (const float*)d_in[8];
    const float* Wo  = (const float*)d_in[9];
    const float* bo  = (const float*)d_in[10];
    float* out = (float*)d_out;

    // ws: adjb 64MB | edge_a 2MB | edge_b 2MB | h_ws 2MB | wgp 48KB | wep 32KB
    char* wsb = (char*)d_ws;
    unsigned short* adjb   = (unsigned short*)wsb;
    unsigned short* edge_a = (unsigned short*)(wsb + 67108864);
    unsigned short* edge_b = (unsigned short*)(wsb + 69206016);
    float*          h_ws   = (float*)(wsb + 71303168);
    unsigned short* wgp    = (unsigned short*)(wsb + 73400320);
    unsigned short* wep    = (unsigned short*)(wsb + 73449472);

    conv_adj<<<dim3(8192), dim3(256), 0, stream>>>(adj, adjb);
    prep_pack<<<dim3(80), dim3(256), 0, stream>>>(Wg, We, wgp, wep);
    init_kernel<<<dim3(ROWS / 4), dim3(256), 0, stream>>>(init_state, We, be, h_ws, edge_a);
    for (int s = 0; s < STEPS; ++s) {
        const unsigned short* ein = (s & 1) ? edge_b : edge_a;
        unsigned short* eo        = (s & 1) ? edge_a : edge_b;
        step_kernel<<<dim3(256), dim3(512), 0, stream>>>(
            adjb, ein, eo, h_ws, wgp, wep, bg, be, (s < STEPS - 1) ? 1 : 0);
    }
    head_kernel<<<dim3(ROWS / 4), dim3(256), 0, stream>>>(h_ws, ann, Wh, bh, Wo, bo, out);
}